// Round 7
// baseline (112.721 us; speedup 1.0000x reference)
//
#include <hip/hip_runtime.h>

typedef __attribute__((ext_vector_type(4))) float f32x4;
typedef __attribute__((ext_vector_type(8))) short short8;
typedef __attribute__((ext_vector_type(4))) unsigned int u32x4;

#define N_ROWS 4096
#define KDIM   4096
#define NC     96     // [cls 0..19][r1 20..40][r2 41..61][pad][det 64..83][pad]
#define GSPLIT 2      // k halves
#define NCH    16     // chunks per block
#define CK     128    // k per chunk

__device__ inline short f2bf(float f) {
  unsigned u = __builtin_bit_cast(unsigned, f);
  u += 0x7FFFu + ((u >> 16) & 1u);   // RNE
  return (short)(u >> 16);
}

__device__ inline unsigned cvtpk(float lo, float hi) {
  unsigned r;
  asm("v_cvt_pk_bf16_f32 %0, %1, %2" : "=v"(r) : "v"(lo), "v"(hi));
  return r;
}

typedef const __attribute__((address_space(1))) void gas_t;
typedef __attribute__((address_space(3))) void las_t;
__device__ __forceinline__ void gll16(const float* g, void* l) {
  __builtin_amdgcn_global_load_lds((gas_t*)g, (las_t*)l, 16, 0, 0);
}

// ---------------- K-1: BW probe (64MB sequential sweep of roi, full occupancy) ----------------
__global__ __launch_bounds__(256) void k_probe(const float* __restrict__ r, float* __restrict__ out) {
  const size_t i = (size_t)blockIdx.x * 256 + threadIdx.x;
  f32x4 s = (f32x4){0.f, 0.f, 0.f, 0.f};
#pragma unroll
  for (int j = 0; j < 8; ++j)
    s += *(const f32x4*)(r + (i + (size_t)j * 524288) * 4);
  out[i] = s[0] + s[1] + s[2] + s[3];
}

// ---------------- K0: pack weights into bf16 B-fragment order (R0-verified mapping) ----------------
__global__ void k_pack(const float* __restrict__ Wcls, const float* __restrict__ Wr1,
                       const float* __restrict__ Wr2, const float* __restrict__ Wdet,
                       ushort* __restrict__ Wp) {
  int t = blockIdx.x * 256 + threadIdx.x;            // 0 .. 128*3072-1
  int K = t / 3072;
  int rem = t - K * 3072;
  int ct = rem >> 9;
  int rem2 = rem & 511;
  int l = rem2 >> 3;
  int j = rem2 & 7;
  int k = K * 32 + (l >> 4) * 8 + j;
  int col = ct * 16 + (l & 15);
  float v = 0.f;
  if (col < 20)                 v = Wcls[k * 20 + col];
  else if (col < 41)            v = Wr1[k * 21 + (col - 20)];
  else if (col < 62)            v = Wr2[k * 21 + (col - 41)];
  else if (col >= 64 && col < 84) v = Wdet[k * 20 + (col - 64)];
  Wp[t] = (ushort)f2bf(v);
}

// ---------------- K1: 16 rows x 2048k per block; 512B-contiguous gll staging; counted vmcnt ----------------
#define WAITV(N) asm volatile("s_waitcnt vmcnt(" #N ")" ::: "memory")
#define SB() __builtin_amdgcn_sched_barrier(0)
#define BUFSEL(C) (((C) & 1) ? buf1 : buf0)
#define BVSEL(C)  (((C) & 1) ? Bv1 : Bv0)

// A chunk: 16 rows x 512B x 3 mats = 24KB; this wave stages rows w*4..w*4+3 (2 pairs x 3 mats = 6 gll)
#define ISSUE_A(C) do {                                                        \
    char* _d = BUFSEL(C);                                                      \
    _Pragma("unroll") for (int m = 0; m < 3; ++m)                              \
      _Pragma("unroll") for (int p = 0; p < 2; ++p)                            \
        gll16(pA[m][p] + (C) * CK, _d + m * 8192 + (w * 4 + 2 * p) * 512);     \
  } while (0)

#define ISSUE_B(C) do {                                                        \
    short8* _bv = BVSEL(C);                                                    \
    const ushort* _p = pb + (size_t)(C) * 12288;                               \
    _Pragma("unroll") for (int ct = 0; ct < 6; ++ct)                           \
      _bv[ct] = *(const short8*)(_p + ct * 512);                               \
  } while (0)

#define COMPUTE(C) do {                                                        \
    const char* _b = BUFSEL(C); const short8* _bv = BVSEL(C);                  \
    f32x4 r0 = *(const f32x4*)(_b + rl * 512 + (((gb + 0) ^ rx) << 4));        \
    f32x4 r1 = *(const f32x4*)(_b + rl * 512 + (((gb + 1) ^ rx) << 4));        \
    f32x4 f0 = *(const f32x4*)(_b + 8192 + rl * 512 + (((gb + 0) ^ rx) << 4)); \
    f32x4 f1 = *(const f32x4*)(_b + 8192 + rl * 512 + (((gb + 1) ^ rx) << 4)); \
    f32x4 x0 = *(const f32x4*)(_b + 16384 + rl * 512 + (((gb + 0) ^ rx) << 4));\
    f32x4 x1 = *(const f32x4*)(_b + 16384 + rl * 512 + (((gb + 1) ^ rx) << 4));\
    u32x4 uR, uD;                                                              \
    uR.x = cvtpk(r0[0], r0[1]); uR.y = cvtpk(r0[2], r0[3]);                    \
    uR.z = cvtpk(r1[0], r1[1]); uR.w = cvtpk(r1[2], r1[3]);                    \
    uD.x = cvtpk(f0[0] - x0[0], f0[1] - x0[1]);                                \
    uD.y = cvtpk(f0[2] - x0[2], f0[3] - x0[3]);                                \
    uD.z = cvtpk(f1[0] - x1[0], f1[1] - x1[1]);                                \
    uD.w = cvtpk(f1[2] - x1[2], f1[3] - x1[3]);                                \
    const short8 aR = __builtin_bit_cast(short8, uR);                          \
    const short8 aD = __builtin_bit_cast(short8, uD);                          \
    _Pragma("unroll") for (int ct = 0; ct < 6; ++ct)                           \
      acc[ct] = __builtin_amdgcn_mfma_f32_16x16x32_bf16(                       \
          ct < 4 ? aR : aD, _bv[ct], acc[ct], 0, 0, 0);                        \
  } while (0)

#define CHUNKI(C, NW) do {                                                     \
    WAITV(NW); SB();                                                           \
    __builtin_amdgcn_s_barrier(); SB();                                        \
    COMPUTE(C); SB();                                                          \
    __builtin_amdgcn_s_barrier(); SB();                                        \
    if ((C) + 2 < NCH) { ISSUE_A((C) + 2); ISSUE_B((C) + 2); SB(); }           \
  } while (0)

__global__ __launch_bounds__(256) void k_gemm(const float* __restrict__ roi,
    const float* __restrict__ frame, const float* __restrict__ ctx,
    const ushort* __restrict__ Wp, float* __restrict__ Spart) {
  __shared__ alignas(16) char buf0[24576];
  __shared__ alignas(16) char buf1[24576];
  const int t    = threadIdx.x;
  const int lane = t & 63;
  const int w    = t >> 6;            // wave 0..3 = kstep-within-chunk
  const int rt   = blockIdx.x & 255;  // 16-row tile
  const int g    = blockIdx.x >> 8;   // k half (2048)

  // stage-side: gll j=(m,p): lane covers row w*4+2p+(lane>>5), 512B granule (lane&31)^(row&7)
  const int lrow = lane >> 5, lgr = lane & 31;
  const float* pA[3][2];
#pragma unroll
  for (int m = 0; m < 3; ++m)
#pragma unroll
    for (int p = 0; p < 2; ++p) {
      const int rloc = w * 4 + 2 * p + lrow;
      const int gran = lgr ^ (rloc & 7);
      const float* mat = (m == 0 ? roi : m == 1 ? frame : ctx);
      pA[m][p] = mat + (size_t)(rt * 16 + rloc) * KDIM + (size_t)g * (NCH * CK) + gran * 4;
    }
  // B: kstep K = g*64 + c*4 + w ; ushort offset = K*3072 + ct*512 + lane*8
  const ushort* pb = Wp + (size_t)(g * 64 + w) * 3072 + lane * 8;

  // read-side lane geometry
  const int rl = lane & 15, kg = lane >> 4;
  const unsigned rx = (unsigned)(rl & 7);
  const unsigned gb = (unsigned)(w * 8 + kg * 2);

  short8 Bv0[6], Bv1[6];
  f32x4 acc[6];
#pragma unroll
  for (int i = 0; i < 6; ++i) acc[i] = (f32x4){0.f, 0.f, 0.f, 0.f};

  ISSUE_A(0); ISSUE_B(0); SB();
  ISSUE_A(1); ISSUE_B(1); SB();

  CHUNKI(0, 12);  CHUNKI(1, 12);  CHUNKI(2, 12);  CHUNKI(3, 12);
  CHUNKI(4, 12);  CHUNKI(5, 12);  CHUNKI(6, 12);  CHUNKI(7, 12);
  CHUNKI(8, 12);  CHUNKI(9, 12);  CHUNKI(10, 12); CHUNKI(11, 12);
  CHUNKI(12, 12); CHUNKI(13, 12); CHUNKI(14, 12); CHUNKI(15, 0);

  // epilogue: 4-wave k-reduction via LDS (bufs dead), contiguous store
  __syncthreads();
  float* red = (float*)buf0;           // 24KB
  const int rbase = (lane >> 4) * 4;   // C/D: col=lane&15, row=(lane>>4)*4+reg [m89-verified]
  const int col = lane & 15;
#pragma unroll
  for (int ct = 0; ct < 6; ++ct)
#pragma unroll
    for (int r = 0; r < 4; ++r)
      red[(w * 16 + rbase + r) * NC + ct * 16 + col] = acc[ct][r];
  __syncthreads();
  float* outp = Spart + (size_t)g * (N_ROWS * NC) + (size_t)rt * (16 * NC);
#pragma unroll
  for (int q = 0; q < 6; ++q) {
    const int e = t * 6 + q;           // 0..1535
    outp[e] = red[e] + red[1536 + e] + red[3072 + e] + red[4608 + e];
  }
}

// ---------------- K2: fused split-K reduce + per-row softmaxes ----------------
__global__ void k_rr(const float* __restrict__ Spart, const float* __restrict__ bcls,
    const float* __restrict__ br1, const float* __restrict__ br2,
    float* __restrict__ S, float* __restrict__ clsp, float* __restrict__ rp1,
    float* __restrict__ lse1, float* __restrict__ lse2) {
  const int b = blockIdx.x;            // 128 blocks x 32 rows
  const int t = threadIdx.x;
  const int base = b * 3072;
#pragma unroll
  for (int j = 0; j < 12; ++j) {
    const int e = base + j * 256 + t;
    float s = 0.f;
#pragma unroll
    for (int gg = 0; gg < GSPLIT; ++gg) s += Spart[(size_t)gg * (N_ROWS * NC) + e];
    S[e] = s;
  }
  __syncthreads();
  if (t < 32) {
    const int i = b * 32 + t;
    const float* sr = S + (size_t)i * NC;
    float s[21];
    float m = -3.4e38f;
    for (int c = 0; c < 20; ++c) { s[c] = sr[c] + bcls[c]; m = fmaxf(m, s[c]); }
    float sum = 0.f;
    for (int c = 0; c < 20; ++c) { float e = expf(s[c] - m); s[c] = e; sum += e; }
    float inv = 1.f / sum;
    for (int c = 0; c < 20; ++c) clsp[(size_t)i * 20 + c] = s[c] * inv;
    m = -3.4e38f;
    for (int c = 0; c < 21; ++c) { s[c] = sr[20 + c] + br1[c]; m = fmaxf(m, s[c]); }
    sum = 0.f;
    for (int c = 0; c < 21; ++c) { float e = expf(s[c] - m); s[c] = e; sum += e; }
    lse1[i] = m + logf(sum);
    inv = 1.f / sum;
    for (int c = 0; c < 21; ++c) rp1[(size_t)i * 21 + c] = s[c] * inv;
    m = -3.4e38f;
    for (int c = 0; c < 21; ++c) { s[c] = sr[41 + c] + br2[c]; m = fmaxf(m, s[c]); }
    sum = 0.f;
    for (int c = 0; c < 21; ++c) sum += expf(s[c] - m);
    lse2[i] = m + logf(sum);
  }
}

// ---------------- K3: per-column stats + argmaxes -> seed boxes ----------------
__global__ __launch_bounds__(256) void k_col(const float* __restrict__ S,
    const float* __restrict__ clsp, const float* __restrict__ rp1,
    const float* __restrict__ isw, const float* __restrict__ ssb,
    const float* __restrict__ bcls,
    float* __restrict__ dcs, float* __restrict__ b1out, float* __restrict__ b2out) {
  const int c = blockIdx.x;
  const int t = threadIdx.x;
  __shared__ float rv[256];
  __shared__ int ri[256];
  float m = -3.4e38f;
  for (int i = t; i < N_ROWS; i += 256) m = fmaxf(m, S[(size_t)i * NC + 64 + c]);
  rv[t] = m; __syncthreads();
  for (int o = 128; o; o >>= 1) { if (t < o) rv[t] = fmaxf(rv[t], rv[t + o]); __syncthreads(); }
  const float M = rv[0]; __syncthreads();
  float se = 0.f, scd = 0.f, v1b = -3.4e38f, v2b = -3.4e38f;
  int i1 = 0, i2 = 0;
  for (int i = t; i < N_ROWS; i += 256) {
    float w = isw[i];
    float e = expf(S[(size_t)i * NC + 64 + c] - M);
    se += e;
    scd += (S[(size_t)i * NC + c] + bcls[c]) * e;
    float v1 = clsp[(size_t)i * 20 + c] * e * w;
    if (v1 > v1b) { v1b = v1; i1 = i; }
    float v2 = rp1[(size_t)i * 21 + c + 1] * w;
    if (v2 > v2b) { v2b = v2; i2 = i; }
  }
  rv[t] = se; __syncthreads();
  for (int o = 128; o; o >>= 1) { if (t < o) rv[t] += rv[t + o]; __syncthreads(); }
  const float SE = rv[0]; __syncthreads();
  rv[t] = scd; __syncthreads();
  for (int o = 128; o; o >>= 1) { if (t < o) rv[t] += rv[t + o]; __syncthreads(); }
  const float SCD = rv[0]; __syncthreads();
  rv[t] = v1b; ri[t] = i1; __syncthreads();
  for (int o = 128; o; o >>= 1) {
    if (t < o) { if (rv[t + o] > rv[t] || (rv[t + o] == rv[t] && ri[t + o] < ri[t])) { rv[t] = rv[t + o]; ri[t] = ri[t + o]; } }
    __syncthreads();
  }
  const int I1 = ri[0]; __syncthreads();
  rv[t] = v2b; ri[t] = i2; __syncthreads();
  for (int o = 128; o; o >>= 1) {
    if (t < o) { if (rv[t + o] > rv[t] || (rv[t + o] == rv[t] && ri[t + o] < ri[t])) { rv[t] = rv[t + o]; ri[t] = ri[t + o]; } }
    __syncthreads();
  }
  const int I2 = ri[0];
  if (t == 0) {
    dcs[c] = SCD / SE;
    for (int q = 0; q < 4; ++q) {
      b1out[c * 4 + q] = ssb[(size_t)I1 * 5 + 1 + q];
      b2out[c * 4 + q] = ssb[(size_t)I2 * 5 + 1 + q];
    }
  }
}

// ---------------- K4: per-row IoU supervision + refine-loss partials ----------------
__global__ __launch_bounds__(256) void k_sup(const float* __restrict__ S,
    const float* __restrict__ ssb, const float* __restrict__ isw,
    const int* __restrict__ label,
    const float* __restrict__ b1in, const float* __restrict__ b2in,
    const float* __restrict__ lse1, const float* __restrict__ lse2,
    const float* __restrict__ br1, const float* __restrict__ br2,
    float* __restrict__ scal) {
  __shared__ float q1[20][4], q2[20][4], a1[20], a2[20];
  __shared__ int pos[20];
  const int t = threadIdx.x;
  if (t < 20) {
    for (int q = 0; q < 4; ++q) { q1[t][q] = b1in[t * 4 + q]; q2[t][q] = b2in[t * 4 + q]; }
    a1[t] = (q1[t][2] - q1[t][0] + 1.f) * (q1[t][3] - q1[t][1] + 1.f);
    a2[t] = (q2[t][2] - q2[t][0] + 1.f) * (q2[t][3] - q2[t][1] + 1.f);
    pos[t] = (label[t] == 1);
  }
  __syncthreads();
  const int i = blockIdx.x * 256 + t;
  const float bx1 = ssb[(size_t)i * 5 + 1], by1 = ssb[(size_t)i * 5 + 2];
  const float bx2 = ssb[(size_t)i * 5 + 3], by2 = ssb[(size_t)i * 5 + 4];
  const float ab = (bx2 - bx1 + 1.f) * (by2 - by1 + 1.f);
  const float w = isw[i];
  float p1 = 0.f, n1 = 0.f, p2 = 0.f, n2 = 0.f;
  {
    float mo = -2.f; int gt = 0;
    for (int c = 0; c < 20; ++c) {
      float v = -1.f;
      if (pos[c]) {
        float xx1 = fmaxf(bx1, q1[c][0]), yy1 = fmaxf(by1, q1[c][1]);
        float xx2 = fminf(bx2, q1[c][2]), yy2 = fminf(by2, q1[c][3]);
        float iw = fmaxf(xx2 - xx1 + 1.f, 0.f), ih = fmaxf(yy2 - yy1 + 1.f, 0.f);
        float inter = iw * ih;
        v = inter / (ab + a1[c] - inter);
      }
      if (v > mo) { mo = v; gt = c; }
    }
    bool fg = mo > 0.5f;
    bool bg = (mo >= 0.1f) && (mo < 0.5f);
    if (fg || bg) {
      int col = fg ? gt + 1 : 0;
      float lp = S[(size_t)i * NC + 20 + col] + br1[col] - lse1[i];
      p1 = w * lp; n1 = 1.f;
    }
  }
  {
    float mo = -2.f; int gt = 0;
    for (int c = 0; c < 20; ++c) {
      float v = -1.f;
      if (pos[c]) {
        float xx1 = fmaxf(bx1, q2[c][0]), yy1 = fmaxf(by1, q2[c][1]);
        float xx2 = fminf(bx2, q2[c][2]), yy2 = fminf(by2, q2[c][3]);
        float iw = fmaxf(xx2 - xx1 + 1.f, 0.f), ih = fmaxf(yy2 - yy1 + 1.f, 0.f);
        float inter = iw * ih;
        v = inter / (ab + a2[c] - inter);
      }
      if (v > mo) { mo = v; gt = c; }
    }
    bool fg = mo > 0.5f;
    bool bg = (mo >= 0.1f) && (mo < 0.5f);
    if (fg || bg) {
      int col = fg ? gt + 1 : 0;
      float lp = S[(size_t)i * NC + 41 + col] + br2[col] - lse2[i];
      p2 = w * lp; n2 = 1.f;
    }
  }
  __shared__ float rs[256];
  float sums[4] = {p1, n1, p2, n2};
  float tot[4];
  for (int q = 0; q < 4; ++q) {
    rs[t] = sums[q]; __syncthreads();
    for (int o = 128; o; o >>= 1) { if (t < o) rs[t] += rs[t + o]; __syncthreads(); }
    tot[q] = rs[0]; __syncthreads();
  }
  if (t == 0) {
    atomicAdd(&scal[0], tot[0]); atomicAdd(&scal[1], tot[1]);
    atomicAdd(&scal[2], tot[2]); atomicAdd(&scal[3], tot[3]);
  }
}

// ---------------- K5: final scalar ----------------
__global__ void k_final(const float* __restrict__ dcs, const int* __restrict__ label,
                        const float* __restrict__ scal, float* __restrict__ out) {
  if (threadIdx.x == 0 && blockIdx.x == 0) {
    float cd = 0.f;
    for (int c = 0; c < 20; ++c) {
      float lab = (float)label[c];
      cd += fmaxf(1.f - lab * dcs[c], 0.f);
    }
    cd *= (1.f / 20.f);
    float rl1 = -scal[0] / scal[1];
    float rl2 = -scal[2] / scal[3];
    out[0] = cd + 0.1f * (rl1 + rl2);
  }
}

// ---------------- workspace layout (all 16B aligned) ----------------
constexpr size_t OFF_S     = 0;                               // 1572864
constexpr size_t OFF_SCAL  = OFF_S + (size_t)N_ROWS * NC * 4; // 16
constexpr size_t OFF_DCS   = OFF_SCAL + 16;                   // 80
constexpr size_t OFF_B1    = OFF_DCS + 80;                    // 320
constexpr size_t OFF_B2    = OFF_B1 + 320;                    // 320
constexpr size_t OFF_LSE1  = OFF_B2 + 320;                    // 16384
constexpr size_t OFF_LSE2  = OFF_LSE1 + 16384;                // 16384
constexpr size_t OFF_CLSP  = OFF_LSE2 + 16384;                // 327680
constexpr size_t OFF_RP1   = OFF_CLSP + 327680;               // 344064
constexpr size_t OFF_WP    = OFF_RP1 + 344064;                // 786432
constexpr size_t OFF_SPART = OFF_WP + 786432;                 // 2*4096*96*4 = 3145728
constexpr size_t OFF_PROBE = OFF_SPART + (size_t)GSPLIT * N_ROWS * NC * 4;  // 2097152

extern "C" void kernel_launch(void* const* d_in, const int* in_sizes, int n_in,
                              void* d_out, int out_size, void* d_ws, size_t ws_size,
                              hipStream_t stream) {
  const float* roi   = (const float*)d_in[0];
  const float* ctx   = (const float*)d_in[1];
  const float* frame = (const float*)d_in[2];
  const float* Wcls  = (const float*)d_in[3];
  const float* bcls  = (const float*)d_in[4];
  const float* Wdet  = (const float*)d_in[5];
  const float* Wr1   = (const float*)d_in[7];
  const float* br1   = (const float*)d_in[8];
  const float* Wr2   = (const float*)d_in[9];
  const float* br2   = (const float*)d_in[10];
  const float* ssb   = (const float*)d_in[11];
  const float* isw   = (const float*)d_in[12];
  const int*   label = (const int*)d_in[13];

  char* ws = (char*)d_ws;
  float*  S     = (float*)(ws + OFF_S);
  float*  scal  = (float*)(ws + OFF_SCAL);
  float*  dcs   = (float*)(ws + OFF_DCS);
  float*  b1    = (float*)(ws + OFF_B1);
  float*  b2    = (float*)(ws + OFF_B2);
  float*  lse1  = (float*)(ws + OFF_LSE1);
  float*  lse2  = (float*)(ws + OFF_LSE2);
  float*  clsp  = (float*)(ws + OFF_CLSP);
  float*  rp1   = (float*)(ws + OFF_RP1);
  ushort* Wp    = (ushort*)(ws + OFF_WP);
  float*  Spart = (float*)(ws + OFF_SPART);
  float*  probe = (float*)(ws + OFF_PROBE);

  hipMemsetAsync(scal, 0, 16, stream);
  k_probe<<<2048, 256, 0, stream>>>(roi, probe);
  k_pack<<<1536, 256, 0, stream>>>(Wcls, Wr1, Wr2, Wdet, Wp);
  k_gemm<<<512, 256, 0, stream>>>(roi, frame, ctx, Wp, Spart);
  k_rr<<<128, 256, 0, stream>>>(Spart, bcls, br1, br2, S, clsp, rp1, lse1, lse2);
  k_col<<<20, 256, 0, stream>>>(S, clsp, rp1, isw, ssb, bcls, dcs, b1, b2);
  k_sup<<<16, 256, 0, stream>>>(S, ssb, isw, label, b1, b2, lse1, lse2, br1, br2, scal);
  k_final<<<1, 64, 0, stream>>>(dcs, label, scal, (float*)d_out);
}

// Round 8
// 98.613 us; speedup vs baseline: 1.1431x; 1.1431x over previous
//
#include <hip/hip_runtime.h>

typedef __attribute__((ext_vector_type(4))) float f32x4;
typedef __attribute__((ext_vector_type(8))) short short8;
typedef __attribute__((ext_vector_type(4))) unsigned int u32x4;

#define N_ROWS 4096
#define KDIM   4096
#define NC     96     // [cls 0..19][r1 20..40][r2 41..61][pad][det 64..83][pad]
#define GSPLIT 4      // k quarters
#define NCH    8      // chunks per block
#define CK     128    // k per chunk

__device__ inline short f2bf(float f) {
  unsigned u = __builtin_bit_cast(unsigned, f);
  u += 0x7FFFu + ((u >> 16) & 1u);   // RNE
  return (short)(u >> 16);
}

__device__ inline unsigned cvtpk(float lo, float hi) {
  unsigned r;
  asm("v_cvt_pk_bf16_f32 %0, %1, %2" : "=v"(r) : "v"(lo), "v"(hi));
  return r;
}

typedef const __attribute__((address_space(1))) void gas_t;
typedef __attribute__((address_space(3))) void las_t;
__device__ __forceinline__ void gll16(const float* g, void* l) {
  __builtin_amdgcn_global_load_lds((gas_t*)g, (las_t*)l, 16, 0, 0);
}

// ---------------- K0: pack weights into bf16 B-fragment order (R0-verified mapping) ----------------
__global__ void k_pack(const float* __restrict__ Wcls, const float* __restrict__ Wr1,
                       const float* __restrict__ Wr2, const float* __restrict__ Wdet,
                       ushort* __restrict__ Wp) {
  int t = blockIdx.x * 256 + threadIdx.x;            // 0 .. 128*3072-1
  int K = t / 3072;
  int rem = t - K * 3072;
  int ct = rem >> 9;
  int rem2 = rem & 511;
  int l = rem2 >> 3;
  int j = rem2 & 7;
  int k = K * 32 + (l >> 4) * 8 + j;
  int col = ct * 16 + (l & 15);
  float v = 0.f;
  if (col < 20)                 v = Wcls[k * 20 + col];
  else if (col < 41)            v = Wr1[k * 21 + (col - 20)];
  else if (col < 62)            v = Wr2[k * 21 + (col - 41)];
  else if (col >= 64 && col < 84) v = Wdet[k * 20 + (col - 64)];
  Wp[t] = (ushort)f2bf(v);
}

// ---------------- K1: 16 rows x 1024k per block; 512B-contiguous gll staging; counted vmcnt ----------------
#define WAITV(N) asm volatile("s_waitcnt vmcnt(" #N ")" ::: "memory")
#define SB() __builtin_amdgcn_sched_barrier(0)
#define BUFSEL(C) (((C) & 1) ? buf1 : buf0)
#define BVSEL(C)  (((C) & 1) ? Bv1 : Bv0)

// A chunk: 16 rows x 512B x 3 mats = 24KB; this wave stages rows w*4..w*4+3 (2 pairs x 3 mats = 6 gll)
#define ISSUE_A(C) do {                                                        \
    char* _d = BUFSEL(C);                                                      \
    _Pragma("unroll") for (int m = 0; m < 3; ++m)                              \
      _Pragma("unroll") for (int p = 0; p < 2; ++p)                            \
        gll16(pA[m][p] + (C) * CK, _d + m * 8192 + (w * 4 + 2 * p) * 512);     \
  } while (0)

#define ISSUE_B(C) do {                                                        \
    short8* _bv = BVSEL(C);                                                    \
    const ushort* _p = pb + (size_t)(C) * 12288;                               \
    _Pragma("unroll") for (int ct = 0; ct < 6; ++ct)                           \
      _bv[ct] = *(const short8*)(_p + ct * 512);                               \
  } while (0)

#define COMPUTE(C) do {                                                        \
    const char* _b = BUFSEL(C); const short8* _bv = BVSEL(C);                  \
    f32x4 r0 = *(const f32x4*)(_b + rl * 512 + (((gb + 0) ^ rx) << 4));        \
    f32x4 r1 = *(const f32x4*)(_b + rl * 512 + (((gb + 1) ^ rx) << 4));        \
    f32x4 f0 = *(const f32x4*)(_b + 8192 + rl * 512 + (((gb + 0) ^ rx) << 4)); \
    f32x4 f1 = *(const f32x4*)(_b + 8192 + rl * 512 + (((gb + 1) ^ rx) << 4)); \
    f32x4 x0 = *(const f32x4*)(_b + 16384 + rl * 512 + (((gb + 0) ^ rx) << 4));\
    f32x4 x1 = *(const f32x4*)(_b + 16384 + rl * 512 + (((gb + 1) ^ rx) << 4));\
    u32x4 uR, uD;                                                              \
    uR.x = cvtpk(r0[0], r0[1]); uR.y = cvtpk(r0[2], r0[3]);                    \
    uR.z = cvtpk(r1[0], r1[1]); uR.w = cvtpk(r1[2], r1[3]);                    \
    uD.x = cvtpk(f0[0] - x0[0], f0[1] - x0[1]);                                \
    uD.y = cvtpk(f0[2] - x0[2], f0[3] - x0[3]);                                \
    uD.z = cvtpk(f1[0] - x1[0], f1[1] - x1[1]);                                \
    uD.w = cvtpk(f1[2] - x1[2], f1[3] - x1[3]);                                \
    const short8 aR = __builtin_bit_cast(short8, uR);                          \
    const short8 aD = __builtin_bit_cast(short8, uD);                          \
    _Pragma("unroll") for (int ct = 0; ct < 6; ++ct)                           \
      acc[ct] = __builtin_amdgcn_mfma_f32_16x16x32_bf16(                       \
          ct < 4 ? aR : aD, _bv[ct], acc[ct], 0, 0, 0);                        \
  } while (0)

#define CHUNKI(C, NW) do {                                                     \
    WAITV(NW); SB();                                                           \
    __builtin_amdgcn_s_barrier(); SB();                                        \
    COMPUTE(C); SB();                                                          \
    __builtin_amdgcn_s_barrier(); SB();                                        \
    if ((C) + 2 < NCH) { ISSUE_A((C) + 2); ISSUE_B((C) + 2); SB(); }           \
  } while (0)

__global__ __launch_bounds__(256) void k_gemm(const float* __restrict__ roi,
    const float* __restrict__ frame, const float* __restrict__ ctx,
    const ushort* __restrict__ Wp, float* __restrict__ Spart) {
  __shared__ alignas(16) char buf0[24576];
  __shared__ alignas(16) char buf1[24576];
  const int t    = threadIdx.x;
  const int lane = t & 63;
  const int w    = t >> 6;            // wave 0..3 = kstep-within-chunk
  const int rt   = blockIdx.x >> 2;   // 16-row tile (4 consecutive blocks share rows)
  const int g    = blockIdx.x & 3;    // k quarter (1024 floats)

  // stage-side: gll j=(m,p): lane covers row w*4+2p+(lane>>5), 512B granule (lane&31)^(row&7)
  const int lrow = lane >> 5, lgr = lane & 31;
  const float* pA[3][2];
#pragma unroll
  for (int m = 0; m < 3; ++m)
#pragma unroll
    for (int p = 0; p < 2; ++p) {
      const int rloc = w * 4 + 2 * p + lrow;
      const int gran = lgr ^ (rloc & 7);
      const float* mat = (m == 0 ? roi : m == 1 ? frame : ctx);
      pA[m][p] = mat + (size_t)(rt * 16 + rloc) * KDIM + (size_t)g * (NCH * CK) + gran * 4;
    }
  // B: kstep K = g*32 + c*4 + w ; ushort offset = K*3072 + ct*512 + lane*8
  const ushort* pb = Wp + (size_t)(g * 32 + w) * 3072 + lane * 8;

  // read-side lane geometry
  const int rl = lane & 15, kg = lane >> 4;
  const unsigned rx = (unsigned)(rl & 7);
  const unsigned gb = (unsigned)(w * 8 + kg * 2);

  short8 Bv0[6], Bv1[6];
  f32x4 acc[6];
#pragma unroll
  for (int i = 0; i < 6; ++i) acc[i] = (f32x4){0.f, 0.f, 0.f, 0.f};

  ISSUE_A(0); ISSUE_B(0); SB();
  ISSUE_A(1); ISSUE_B(1); SB();

  CHUNKI(0, 12);  CHUNKI(1, 12);  CHUNKI(2, 12);  CHUNKI(3, 12);
  CHUNKI(4, 12);  CHUNKI(5, 12);  CHUNKI(6, 12);  CHUNKI(7, 0);

  // epilogue: 4-wave k-reduction via LDS (bufs dead), contiguous store
  __syncthreads();
  float* red = (float*)buf0;           // 24KB
  const int rbase = (lane >> 4) * 4;   // C/D: col=lane&15, row=(lane>>4)*4+reg [m89-verified]
  const int col = lane & 15;
#pragma unroll
  for (int ct = 0; ct < 6; ++ct)
#pragma unroll
    for (int r = 0; r < 4; ++r)
      red[(w * 16 + rbase + r) * NC + ct * 16 + col] = acc[ct][r];
  __syncthreads();
  float* outp = Spart + (size_t)g * (N_ROWS * NC) + (size_t)rt * (16 * NC);
#pragma unroll
  for (int q = 0; q < 6; ++q) {
    const int e = t * 6 + q;           // 0..1535
    outp[e] = red[e] + red[1536 + e] + red[3072 + e] + red[4608 + e];
  }
}

// ---------------- K2: fused split-K reduce + per-row softmaxes ----------------
__global__ void k_rr(const float* __restrict__ Spart, const float* __restrict__ bcls,
    const float* __restrict__ br1, const float* __restrict__ br2,
    float* __restrict__ S, float* __restrict__ clsp, float* __restrict__ rp1,
    float* __restrict__ lse1, float* __restrict__ lse2) {
  const int b = blockIdx.x;            // 128 blocks x 32 rows
  const int t = threadIdx.x;
  const int base = b * 3072;
#pragma unroll
  for (int j = 0; j < 12; ++j) {
    const int e = base + j * 256 + t;
    float s = 0.f;
#pragma unroll
    for (int gg = 0; gg < GSPLIT; ++gg) s += Spart[(size_t)gg * (N_ROWS * NC) + e];
    S[e] = s;
  }
  __syncthreads();
  if (t < 32) {
    const int i = b * 32 + t;
    const float* sr = S + (size_t)i * NC;
    float s[21];
    float m = -3.4e38f;
    for (int c = 0; c < 20; ++c) { s[c] = sr[c] + bcls[c]; m = fmaxf(m, s[c]); }
    float sum = 0.f;
    for (int c = 0; c < 20; ++c) { float e = expf(s[c] - m); s[c] = e; sum += e; }
    float inv = 1.f / sum;
    for (int c = 0; c < 20; ++c) clsp[(size_t)i * 20 + c] = s[c] * inv;
    m = -3.4e38f;
    for (int c = 0; c < 21; ++c) { s[c] = sr[20 + c] + br1[c]; m = fmaxf(m, s[c]); }
    sum = 0.f;
    for (int c = 0; c < 21; ++c) { float e = expf(s[c] - m); s[c] = e; sum += e; }
    lse1[i] = m + logf(sum);
    inv = 1.f / sum;
    for (int c = 0; c < 21; ++c) rp1[(size_t)i * 21 + c] = s[c] * inv;
    m = -3.4e38f;
    for (int c = 0; c < 21; ++c) { s[c] = sr[41 + c] + br2[c]; m = fmaxf(m, s[c]); }
    sum = 0.f;
    for (int c = 0; c < 21; ++c) sum += expf(s[c] - m);
    lse2[i] = m + logf(sum);
  }
}

// ---------------- K3: per-column stats + argmaxes -> seed boxes ----------------
__global__ __launch_bounds__(256) void k_col(const float* __restrict__ S,
    const float* __restrict__ clsp, const float* __restrict__ rp1,
    const float* __restrict__ isw, const float* __restrict__ ssb,
    const float* __restrict__ bcls,
    float* __restrict__ dcs, float* __restrict__ b1out, float* __restrict__ b2out) {
  const int c = blockIdx.x;
  const int t = threadIdx.x;
  __shared__ float rv[256];
  __shared__ int ri[256];
  float m = -3.4e38f;
  for (int i = t; i < N_ROWS; i += 256) m = fmaxf(m, S[(size_t)i * NC + 64 + c]);
  rv[t] = m; __syncthreads();
  for (int o = 128; o; o >>= 1) { if (t < o) rv[t] = fmaxf(rv[t], rv[t + o]); __syncthreads(); }
  const float M = rv[0]; __syncthreads();
  float se = 0.f, scd = 0.f, v1b = -3.4e38f, v2b = -3.4e38f;
  int i1 = 0, i2 = 0;
  for (int i = t; i < N_ROWS; i += 256) {
    float w = isw[i];
    float e = expf(S[(size_t)i * NC + 64 + c] - M);
    se += e;
    scd += (S[(size_t)i * NC + c] + bcls[c]) * e;
    float v1 = clsp[(size_t)i * 20 + c] * e * w;
    if (v1 > v1b) { v1b = v1; i1 = i; }
    float v2 = rp1[(size_t)i * 21 + c + 1] * w;
    if (v2 > v2b) { v2b = v2; i2 = i; }
  }
  rv[t] = se; __syncthreads();
  for (int o = 128; o; o >>= 1) { if (t < o) rv[t] += rv[t + o]; __syncthreads(); }
  const float SE = rv[0]; __syncthreads();
  rv[t] = scd; __syncthreads();
  for (int o = 128; o; o >>= 1) { if (t < o) rv[t] += rv[t + o]; __syncthreads(); }
  const float SCD = rv[0]; __syncthreads();
  rv[t] = v1b; ri[t] = i1; __syncthreads();
  for (int o = 128; o; o >>= 1) {
    if (t < o) { if (rv[t + o] > rv[t] || (rv[t + o] == rv[t] && ri[t + o] < ri[t])) { rv[t] = rv[t + o]; ri[t] = ri[t + o]; } }
    __syncthreads();
  }
  const int I1 = ri[0]; __syncthreads();
  rv[t] = v2b; ri[t] = i2; __syncthreads();
  for (int o = 128; o; o >>= 1) {
    if (t < o) { if (rv[t + o] > rv[t] || (rv[t + o] == rv[t] && ri[t + o] < ri[t])) { rv[t] = rv[t + o]; ri[t] = ri[t + o]; } }
    __syncthreads();
  }
  const int I2 = ri[0];
  if (t == 0) {
    dcs[c] = SCD / SE;
    for (int q = 0; q < 4; ++q) {
      b1out[c * 4 + q] = ssb[(size_t)I1 * 5 + 1 + q];
      b2out[c * 4 + q] = ssb[(size_t)I2 * 5 + 1 + q];
    }
  }
}

// ---------------- K4: per-row IoU supervision + refine-loss partials ----------------
__global__ __launch_bounds__(256) void k_sup(const float* __restrict__ S,
    const float* __restrict__ ssb, const float* __restrict__ isw,
    const int* __restrict__ label,
    const float* __restrict__ b1in, const float* __restrict__ b2in,
    const float* __restrict__ lse1, const float* __restrict__ lse2,
    const float* __restrict__ br1, const float* __restrict__ br2,
    float* __restrict__ scal) {
  __shared__ float q1[20][4], q2[20][4], a1[20], a2[20];
  __shared__ int pos[20];
  const int t = threadIdx.x;
  if (t < 20) {
    for (int q = 0; q < 4; ++q) { q1[t][q] = b1in[t * 4 + q]; q2[t][q] = b2in[t * 4 + q]; }
    a1[t] = (q1[t][2] - q1[t][0] + 1.f) * (q1[t][3] - q1[t][1] + 1.f);
    a2[t] = (q2[t][2] - q2[t][0] + 1.f) * (q2[t][3] - q2[t][1] + 1.f);
    pos[t] = (label[t] == 1);
  }
  __syncthreads();
  const int i = blockIdx.x * 256 + t;
  const float bx1 = ssb[(size_t)i * 5 + 1], by1 = ssb[(size_t)i * 5 + 2];
  const float bx2 = ssb[(size_t)i * 5 + 3], by2 = ssb[(size_t)i * 5 + 4];
  const float ab = (bx2 - bx1 + 1.f) * (by2 - by1 + 1.f);
  const float w = isw[i];
  float p1 = 0.f, n1 = 0.f, p2 = 0.f, n2 = 0.f;
  {
    float mo = -2.f; int gt = 0;
    for (int c = 0; c < 20; ++c) {
      float v = -1.f;
      if (pos[c]) {
        float xx1 = fmaxf(bx1, q1[c][0]), yy1 = fmaxf(by1, q1[c][1]);
        float xx2 = fminf(bx2, q1[c][2]), yy2 = fminf(by2, q1[c][3]);
        float iw = fmaxf(xx2 - xx1 + 1.f, 0.f), ih = fmaxf(yy2 - yy1 + 1.f, 0.f);
        float inter = iw * ih;
        v = inter / (ab + a1[c] - inter);
      }
      if (v > mo) { mo = v; gt = c; }
    }
    bool fg = mo > 0.5f;
    bool bg = (mo >= 0.1f) && (mo < 0.5f);
    if (fg || bg) {
      int col = fg ? gt + 1 : 0;
      float lp = S[(size_t)i * NC + 20 + col] + br1[col] - lse1[i];
      p1 = w * lp; n1 = 1.f;
    }
  }
  {
    float mo = -2.f; int gt = 0;
    for (int c = 0; c < 20; ++c) {
      float v = -1.f;
      if (pos[c]) {
        float xx1 = fmaxf(bx1, q2[c][0]), yy1 = fmaxf(by1, q2[c][1]);
        float xx2 = fminf(bx2, q2[c][2]), yy2 = fminf(by2, q2[c][3]);
        float iw = fmaxf(xx2 - xx1 + 1.f, 0.f), ih = fmaxf(yy2 - yy1 + 1.f, 0.f);
        float inter = iw * ih;
        v = inter / (ab + a2[c] - inter);
      }
      if (v > mo) { mo = v; gt = c; }
    }
    bool fg = mo > 0.5f;
    bool bg = (mo >= 0.1f) && (mo < 0.5f);
    if (fg || bg) {
      int col = fg ? gt + 1 : 0;
      float lp = S[(size_t)i * NC + 41 + col] + br2[col] - lse2[i];
      p2 = w * lp; n2 = 1.f;
    }
  }
  __shared__ float rs[256];
  float sums[4] = {p1, n1, p2, n2};
  float tot[4];
  for (int q = 0; q < 4; ++q) {
    rs[t] = sums[q]; __syncthreads();
    for (int o = 128; o; o >>= 1) { if (t < o) rs[t] += rs[t + o]; __syncthreads(); }
    tot[q] = rs[0]; __syncthreads();
  }
  if (t == 0) {
    atomicAdd(&scal[0], tot[0]); atomicAdd(&scal[1], tot[1]);
    atomicAdd(&scal[2], tot[2]); atomicAdd(&scal[3], tot[3]);
  }
}

// ---------------- K5: final scalar ----------------
__global__ void k_final(const float* __restrict__ dcs, const int* __restrict__ label,
                        const float* __restrict__ scal, float* __restrict__ out) {
  if (threadIdx.x == 0 && blockIdx.x == 0) {
    float cd = 0.f;
    for (int c = 0; c < 20; ++c) {
      float lab = (float)label[c];
      cd += fmaxf(1.f - lab * dcs[c], 0.f);
    }
    cd *= (1.f / 20.f);
    float rl1 = -scal[0] / scal[1];
    float rl2 = -scal[2] / scal[3];
    out[0] = cd + 0.1f * (rl1 + rl2);
  }
}

// ---------------- workspace layout (all 16B aligned) ----------------
constexpr size_t OFF_S     = 0;                               // 1572864
constexpr size_t OFF_SCAL  = OFF_S + (size_t)N_ROWS * NC * 4; // 16
constexpr size_t OFF_DCS   = OFF_SCAL + 16;                   // 80
constexpr size_t OFF_B1    = OFF_DCS + 80;                    // 320
constexpr size_t OFF_B2    = OFF_B1 + 320;                    // 320
constexpr size_t OFF_LSE1  = OFF_B2 + 320;                    // 16384
constexpr size_t OFF_LSE2  = OFF_LSE1 + 16384;                // 16384
constexpr size_t OFF_CLSP  = OFF_LSE2 + 16384;                // 327680
constexpr size_t OFF_RP1   = OFF_CLSP + 327680;               // 344064
constexpr size_t OFF_WP    = OFF_RP1 + 344064;                // 786432
constexpr size_t OFF_SPART = OFF_WP + 786432;                 // 4*4096*96*4 = 6291456

extern "C" void kernel_launch(void* const* d_in, const int* in_sizes, int n_in,
                              void* d_out, int out_size, void* d_ws, size_t ws_size,
                              hipStream_t stream) {
  const float* roi   = (const float*)d_in[0];
  const float* ctx   = (const float*)d_in[1];
  const float* frame = (const float*)d_in[2];
  const float* Wcls  = (const float*)d_in[3];
  const float* bcls  = (const float*)d_in[4];
  const float* Wdet  = (const float*)d_in[5];
  const float* Wr1   = (const float*)d_in[7];
  const float* br1   = (const float*)d_in[8];
  const float* Wr2   = (const float*)d_in[9];
  const float* br2   = (const float*)d_in[10];
  const float* ssb   = (const float*)d_in[11];
  const float* isw   = (const float*)d_in[12];
  const int*   label = (const int*)d_in[13];

  char* ws = (char*)d_ws;
  float*  S     = (float*)(ws + OFF_S);
  float*  scal  = (float*)(ws + OFF_SCAL);
  float*  dcs   = (float*)(ws + OFF_DCS);
  float*  b1    = (float*)(ws + OFF_B1);
  float*  b2    = (float*)(ws + OFF_B2);
  float*  lse1  = (float*)(ws + OFF_LSE1);
  float*  lse2  = (float*)(ws + OFF_LSE2);
  float*  clsp  = (float*)(ws + OFF_CLSP);
  float*  rp1   = (float*)(ws + OFF_RP1);
  ushort* Wp    = (ushort*)(ws + OFF_WP);
  float*  Spart = (float*)(ws + OFF_SPART);

  hipMemsetAsync(scal, 0, 16, stream);
  k_pack<<<1536, 256, 0, stream>>>(Wcls, Wr1, Wr2, Wdet, Wp);
  k_gemm<<<1024, 256, 0, stream>>>(roi, frame, ctx, Wp, Spart);
  k_rr<<<128, 256, 0, stream>>>(Spart, bcls, br1, br2, S, clsp, rp1, lse1, lse2);
  k_col<<<20, 256, 0, stream>>>(S, clsp, rp1, isw, ssb, bcls, dcs, b1, b2);
  k_sup<<<16, 256, 0, stream>>>(S, ssb, isw, label, b1, b2, lse1, lse2, br1, br2, scal);
  k_final<<<1, 64, 0, stream>>>(dcs, label, scal, (float*)d_out);
}

// Round 9
// 87.470 us; speedup vs baseline: 1.2887x; 1.1274x over previous
//
#include <hip/hip_runtime.h>

typedef __attribute__((ext_vector_type(4))) float f32x4;
typedef __attribute__((ext_vector_type(8))) short short8;
typedef __attribute__((ext_vector_type(4))) unsigned int u32x4;

#define N_ROWS 4096
#define KDIM   4096
#define NC     96     // [cls 0..19][r1 20..40][r2 41..61][pad][det 64..83][pad]
#define GSPLIT 2      // k halves
#define NCH    16     // chunks per block
#define CK     128    // k per chunk

__device__ inline short f2bf(float f) {
  unsigned u = __builtin_bit_cast(unsigned, f);
  u += 0x7FFFu + ((u >> 16) & 1u);   // RNE
  return (short)(u >> 16);
}

__device__ inline unsigned cvtpk(float lo, float hi) {
  unsigned r;
  asm("v_cvt_pk_bf16_f32 %0, %1, %2" : "=v"(r) : "v"(lo), "v"(hi));
  return r;
}

typedef const __attribute__((address_space(1))) void gas_t;
typedef __attribute__((address_space(3))) void las_t;
__device__ __forceinline__ void gll16(const float* g, void* l) {
  __builtin_amdgcn_global_load_lds((gas_t*)g, (las_t*)l, 16, 0, 0);
}

// ---------------- K0: pack weights into bf16 B-fragment order (R0-verified mapping) ----------------
__global__ void k_pack(const float* __restrict__ Wcls, const float* __restrict__ Wr1,
                       const float* __restrict__ Wr2, const float* __restrict__ Wdet,
                       ushort* __restrict__ Wp) {
  int t = blockIdx.x * 256 + threadIdx.x;            // 0 .. 128*3072-1
  int K = t / 3072;
  int rem = t - K * 3072;
  int ct = rem >> 9;
  int rem2 = rem & 511;
  int l = rem2 >> 3;
  int j = rem2 & 7;
  int k = K * 32 + (l >> 4) * 8 + j;
  int col = ct * 16 + (l & 15);
  float v = 0.f;
  if (col < 20)                 v = Wcls[k * 20 + col];
  else if (col < 41)            v = Wr1[k * 21 + (col - 20)];
  else if (col < 62)            v = Wr2[k * 21 + (col - 41)];
  else if (col >= 64 && col < 84) v = Wdet[k * 20 + (col - 64)];
  Wp[t] = (ushort)f2bf(v);
}

// ---------------- K1: 16 rows x 2048k per block; 512B-contiguous gll staging; counted vmcnt ----------------
#define WAITV(N) asm volatile("s_waitcnt vmcnt(" #N ")" ::: "memory")
#define SB() __builtin_amdgcn_sched_barrier(0)
#define BUFSEL(C) (((C) & 1) ? buf1 : buf0)
#define BVSEL(C)  (((C) & 1) ? Bv1 : Bv0)

// A chunk: 16 rows x 512B x 3 mats = 24KB; this wave stages rows w*4..w*4+3 (2 pairs x 3 mats = 6 gll)
#define ISSUE_A(C) do {                                                        \
    char* _d = BUFSEL(C);                                                      \
    _Pragma("unroll") for (int m = 0; m < 3; ++m)                              \
      _Pragma("unroll") for (int p = 0; p < 2; ++p)                            \
        gll16(pA[m][p] + (C) * CK, _d + m * 8192 + (w * 4 + 2 * p) * 512);     \
  } while (0)

#define ISSUE_B(C) do {                                                        \
    short8* _bv = BVSEL(C);                                                    \
    const ushort* _p = pb + (size_t)(C) * 12288;                               \
    _Pragma("unroll") for (int ct = 0; ct < 6; ++ct)                           \
      _bv[ct] = *(const short8*)(_p + ct * 512);                               \
  } while (0)

#define COMPUTE(C) do {                                                        \
    const char* _b = BUFSEL(C); const short8* _bv = BVSEL(C);                  \
    f32x4 r0 = *(const f32x4*)(_b + rl * 512 + (((gb + 0) ^ rx) << 4));        \
    f32x4 r1 = *(const f32x4*)(_b + rl * 512 + (((gb + 1) ^ rx) << 4));        \
    f32x4 f0 = *(const f32x4*)(_b + 8192 + rl * 512 + (((gb + 0) ^ rx) << 4)); \
    f32x4 f1 = *(const f32x4*)(_b + 8192 + rl * 512 + (((gb + 1) ^ rx) << 4)); \
    f32x4 x0 = *(const f32x4*)(_b + 16384 + rl * 512 + (((gb + 0) ^ rx) << 4));\
    f32x4 x1 = *(const f32x4*)(_b + 16384 + rl * 512 + (((gb + 1) ^ rx) << 4));\
    u32x4 uR, uD;                                                              \
    uR.x = cvtpk(r0[0], r0[1]); uR.y = cvtpk(r0[2], r0[3]);                    \
    uR.z = cvtpk(r1[0], r1[1]); uR.w = cvtpk(r1[2], r1[3]);                    \
    uD.x = cvtpk(f0[0] - x0[0], f0[1] - x0[1]);                                \
    uD.y = cvtpk(f0[2] - x0[2], f0[3] - x0[3]);                                \
    uD.z = cvtpk(f1[0] - x1[0], f1[1] - x1[1]);                                \
    uD.w = cvtpk(f1[2] - x1[2], f1[3] - x1[3]);                                \
    const short8 aR = __builtin_bit_cast(short8, uR);                          \
    const short8 aD = __builtin_bit_cast(short8, uD);                          \
    _Pragma("unroll") for (int ct = 0; ct < 6; ++ct)                           \
      acc[ct] = __builtin_amdgcn_mfma_f32_16x16x32_bf16(                       \
          ct < 4 ? aR : aD, _bv[ct], acc[ct], 0, 0, 0);                        \
  } while (0)

#define CHUNKI(C, NW) do {                                                     \
    WAITV(NW); SB();                                                           \
    __builtin_amdgcn_s_barrier(); SB();                                        \
    COMPUTE(C); SB();                                                          \
    __builtin_amdgcn_s_barrier(); SB();                                        \
    if ((C) + 2 < NCH) { ISSUE_A((C) + 2); ISSUE_B((C) + 2); SB(); }           \
  } while (0)

__global__ __launch_bounds__(256) void k_gemm(const float* __restrict__ roi,
    const float* __restrict__ frame, const float* __restrict__ ctx,
    const ushort* __restrict__ Wp, float* __restrict__ Spart) {
  __shared__ alignas(16) char buf0[24576];
  __shared__ alignas(16) char buf1[24576];
  const int t    = threadIdx.x;
  const int lane = t & 63;
  const int w    = t >> 6;            // wave 0..3 = kstep-within-chunk
  const int rt   = blockIdx.x & 255;  // 16-row tile
  const int g    = blockIdx.x >> 8;   // k half (2048)

  // stage-side: gll j=(m,p): lane covers row w*4+2p+(lane>>5), 512B granule (lane&31)^(row&7)
  const int lrow = lane >> 5, lgr = lane & 31;
  const float* pA[3][2];
#pragma unroll
  for (int m = 0; m < 3; ++m)
#pragma unroll
    for (int p = 0; p < 2; ++p) {
      const int rloc = w * 4 + 2 * p + lrow;
      const int gran = lgr ^ (rloc & 7);
      const float* mat = (m == 0 ? roi : m == 1 ? frame : ctx);
      pA[m][p] = mat + (size_t)(rt * 16 + rloc) * KDIM + (size_t)g * (NCH * CK) + gran * 4;
    }
  // B: kstep K = g*64 + c*4 + w ; ushort offset = K*3072 + ct*512 + lane*8
  const ushort* pb = Wp + (size_t)(g * 64 + w) * 3072 + lane * 8;

  // read-side lane geometry
  const int rl = lane & 15, kg = lane >> 4;
  const unsigned rx = (unsigned)(rl & 7);
  const unsigned gb = (unsigned)(w * 8 + kg * 2);

  short8 Bv0[6], Bv1[6];
  f32x4 acc[6];
#pragma unroll
  for (int i = 0; i < 6; ++i) acc[i] = (f32x4){0.f, 0.f, 0.f, 0.f};

  ISSUE_A(0); ISSUE_B(0); SB();
  ISSUE_A(1); ISSUE_B(1); SB();

  CHUNKI(0, 12);  CHUNKI(1, 12);  CHUNKI(2, 12);  CHUNKI(3, 12);
  CHUNKI(4, 12);  CHUNKI(5, 12);  CHUNKI(6, 12);  CHUNKI(7, 12);
  CHUNKI(8, 12);  CHUNKI(9, 12);  CHUNKI(10, 12); CHUNKI(11, 12);
  CHUNKI(12, 12); CHUNKI(13, 12); CHUNKI(14, 12); CHUNKI(15, 0);

  // epilogue: 4-wave k-reduction via LDS (bufs dead), contiguous store
  __syncthreads();
  float* red = (float*)buf0;           // 24KB
  const int rbase = (lane >> 4) * 4;   // C/D: col=lane&15, row=(lane>>4)*4+reg [m89-verified]
  const int col = lane & 15;
#pragma unroll
  for (int ct = 0; ct < 6; ++ct)
#pragma unroll
    for (int r = 0; r < 4; ++r)
      red[(w * 16 + rbase + r) * NC + ct * 16 + col] = acc[ct][r];
  __syncthreads();
  float* outp = Spart + (size_t)g * (N_ROWS * NC) + (size_t)rt * (16 * NC);
#pragma unroll
  for (int q = 0; q < 6; ++q) {
    const int e = t * 6 + q;           // 0..1535
    outp[e] = red[e] + red[1536 + e] + red[3072 + e] + red[4608 + e];
  }
}

// ---------------- K2: fused split-K reduce + per-row softmaxes ----------------
__global__ void k_rr(const float* __restrict__ Spart, const float* __restrict__ bcls,
    const float* __restrict__ br1, const float* __restrict__ br2,
    float* __restrict__ S, float* __restrict__ clsp, float* __restrict__ rp1,
    float* __restrict__ lse1, float* __restrict__ lse2) {
  const int b = blockIdx.x;            // 128 blocks x 32 rows
  const int t = threadIdx.x;
  const int base = b * 3072;
#pragma unroll
  for (int j = 0; j < 12; ++j) {
    const int e = base + j * 256 + t;
    float s = 0.f;
#pragma unroll
    for (int gg = 0; gg < GSPLIT; ++gg) s += Spart[(size_t)gg * (N_ROWS * NC) + e];
    S[e] = s;
  }
  __syncthreads();
  if (t < 32) {
    const int i = b * 32 + t;
    const float* sr = S + (size_t)i * NC;
    float s[21];
    float m = -3.4e38f;
    for (int c = 0; c < 20; ++c) { s[c] = sr[c] + bcls[c]; m = fmaxf(m, s[c]); }
    float sum = 0.f;
    for (int c = 0; c < 20; ++c) { float e = expf(s[c] - m); s[c] = e; sum += e; }
    float inv = 1.f / sum;
    for (int c = 0; c < 20; ++c) clsp[(size_t)i * 20 + c] = s[c] * inv;
    m = -3.4e38f;
    for (int c = 0; c < 21; ++c) { s[c] = sr[20 + c] + br1[c]; m = fmaxf(m, s[c]); }
    sum = 0.f;
    for (int c = 0; c < 21; ++c) { float e = expf(s[c] - m); s[c] = e; sum += e; }
    lse1[i] = m + logf(sum);
    inv = 1.f / sum;
    for (int c = 0; c < 21; ++c) rp1[(size_t)i * 21 + c] = s[c] * inv;
    m = -3.4e38f;
    for (int c = 0; c < 21; ++c) { s[c] = sr[41 + c] + br2[c]; m = fmaxf(m, s[c]); }
    sum = 0.f;
    for (int c = 0; c < 21; ++c) sum += expf(s[c] - m);
    lse2[i] = m + logf(sum);
  }
}

// ---------------- K3: per-column stats + argmaxes -> seed boxes ----------------
__global__ __launch_bounds__(256) void k_col(const float* __restrict__ S,
    const float* __restrict__ clsp, const float* __restrict__ rp1,
    const float* __restrict__ isw, const float* __restrict__ ssb,
    const float* __restrict__ bcls,
    float* __restrict__ dcs, float* __restrict__ b1out, float* __restrict__ b2out) {
  const int c = blockIdx.x;
  const int t = threadIdx.x;
  __shared__ float rv[256];
  __shared__ int ri[256];
  float m = -3.4e38f;
  for (int i = t; i < N_ROWS; i += 256) m = fmaxf(m, S[(size_t)i * NC + 64 + c]);
  rv[t] = m; __syncthreads();
  for (int o = 128; o; o >>= 1) { if (t < o) rv[t] = fmaxf(rv[t], rv[t + o]); __syncthreads(); }
  const float M = rv[0]; __syncthreads();
  float se = 0.f, scd = 0.f, v1b = -3.4e38f, v2b = -3.4e38f;
  int i1 = 0, i2 = 0;
  for (int i = t; i < N_ROWS; i += 256) {
    float w = isw[i];
    float e = expf(S[(size_t)i * NC + 64 + c] - M);
    se += e;
    scd += (S[(size_t)i * NC + c] + bcls[c]) * e;
    float v1 = clsp[(size_t)i * 20 + c] * e * w;
    if (v1 > v1b) { v1b = v1; i1 = i; }
    float v2 = rp1[(size_t)i * 21 + c + 1] * w;
    if (v2 > v2b) { v2b = v2; i2 = i; }
  }
  rv[t] = se; __syncthreads();
  for (int o = 128; o; o >>= 1) { if (t < o) rv[t] += rv[t + o]; __syncthreads(); }
  const float SE = rv[0]; __syncthreads();
  rv[t] = scd; __syncthreads();
  for (int o = 128; o; o >>= 1) { if (t < o) rv[t] += rv[t + o]; __syncthreads(); }
  const float SCD = rv[0]; __syncthreads();
  rv[t] = v1b; ri[t] = i1; __syncthreads();
  for (int o = 128; o; o >>= 1) {
    if (t < o) { if (rv[t + o] > rv[t] || (rv[t + o] == rv[t] && ri[t + o] < ri[t])) { rv[t] = rv[t + o]; ri[t] = ri[t + o]; } }
    __syncthreads();
  }
  const int I1 = ri[0]; __syncthreads();
  rv[t] = v2b; ri[t] = i2; __syncthreads();
  for (int o = 128; o; o >>= 1) {
    if (t < o) { if (rv[t + o] > rv[t] || (rv[t + o] == rv[t] && ri[t + o] < ri[t])) { rv[t] = rv[t + o]; ri[t] = ri[t + o]; } }
    __syncthreads();
  }
  const int I2 = ri[0];
  if (t == 0) {
    dcs[c] = SCD / SE;
    for (int q = 0; q < 4; ++q) {
      b1out[c * 4 + q] = ssb[(size_t)I1 * 5 + 1 + q];
      b2out[c * 4 + q] = ssb[(size_t)I2 * 5 + 1 + q];
    }
  }
}

// ---------------- K4: per-row IoU supervision + refine-loss partials ----------------
__global__ __launch_bounds__(256) void k_sup(const float* __restrict__ S,
    const float* __restrict__ ssb, const float* __restrict__ isw,
    const int* __restrict__ label,
    const float* __restrict__ b1in, const float* __restrict__ b2in,
    const float* __restrict__ lse1, const float* __restrict__ lse2,
    const float* __restrict__ br1, const float* __restrict__ br2,
    float* __restrict__ scal) {
  __shared__ float q1[20][4], q2[20][4], a1[20], a2[20];
  __shared__ int pos[20];
  const int t = threadIdx.x;
  if (t < 20) {
    for (int q = 0; q < 4; ++q) { q1[t][q] = b1in[t * 4 + q]; q2[t][q] = b2in[t * 4 + q]; }
    a1[t] = (q1[t][2] - q1[t][0] + 1.f) * (q1[t][3] - q1[t][1] + 1.f);
    a2[t] = (q2[t][2] - q2[t][0] + 1.f) * (q2[t][3] - q2[t][1] + 1.f);
    pos[t] = (label[t] == 1);
  }
  __syncthreads();
  const int i = blockIdx.x * 256 + t;
  const float bx1 = ssb[(size_t)i * 5 + 1], by1 = ssb[(size_t)i * 5 + 2];
  const float bx2 = ssb[(size_t)i * 5 + 3], by2 = ssb[(size_t)i * 5 + 4];
  const float ab = (bx2 - bx1 + 1.f) * (by2 - by1 + 1.f);
  const float w = isw[i];
  float p1 = 0.f, n1 = 0.f, p2 = 0.f, n2 = 0.f;
  {
    float mo = -2.f; int gt = 0;
    for (int c = 0; c < 20; ++c) {
      float v = -1.f;
      if (pos[c]) {
        float xx1 = fmaxf(bx1, q1[c][0]), yy1 = fmaxf(by1, q1[c][1]);
        float xx2 = fminf(bx2, q1[c][2]), yy2 = fminf(by2, q1[c][3]);
        float iw = fmaxf(xx2 - xx1 + 1.f, 0.f), ih = fmaxf(yy2 - yy1 + 1.f, 0.f);
        float inter = iw * ih;
        v = inter / (ab + a1[c] - inter);
      }
      if (v > mo) { mo = v; gt = c; }
    }
    bool fg = mo > 0.5f;
    bool bg = (mo >= 0.1f) && (mo < 0.5f);
    if (fg || bg) {
      int col = fg ? gt + 1 : 0;
      float lp = S[(size_t)i * NC + 20 + col] + br1[col] - lse1[i];
      p1 = w * lp; n1 = 1.f;
    }
  }
  {
    float mo = -2.f; int gt = 0;
    for (int c = 0; c < 20; ++c) {
      float v = -1.f;
      if (pos[c]) {
        float xx1 = fmaxf(bx1, q2[c][0]), yy1 = fmaxf(by1, q2[c][1]);
        float xx2 = fminf(bx2, q2[c][2]), yy2 = fminf(by2, q2[c][3]);
        float iw = fmaxf(xx2 - xx1 + 1.f, 0.f), ih = fmaxf(yy2 - yy1 + 1.f, 0.f);
        float inter = iw * ih;
        v = inter / (ab + a2[c] - inter);
      }
      if (v > mo) { mo = v; gt = c; }
    }
    bool fg = mo > 0.5f;
    bool bg = (mo >= 0.1f) && (mo < 0.5f);
    if (fg || bg) {
      int col = fg ? gt + 1 : 0;
      float lp = S[(size_t)i * NC + 41 + col] + br2[col] - lse2[i];
      p2 = w * lp; n2 = 1.f;
    }
  }
  __shared__ float rs[256];
  float sums[4] = {p1, n1, p2, n2};
  float tot[4];
  for (int q = 0; q < 4; ++q) {
    rs[t] = sums[q]; __syncthreads();
    for (int o = 128; o; o >>= 1) { if (t < o) rs[t] += rs[t + o]; __syncthreads(); }
    tot[q] = rs[0]; __syncthreads();
  }
  if (t == 0) {
    atomicAdd(&scal[0], tot[0]); atomicAdd(&scal[1], tot[1]);
    atomicAdd(&scal[2], tot[2]); atomicAdd(&scal[3], tot[3]);
  }
}

// ---------------- K5: final scalar ----------------
__global__ void k_final(const float* __restrict__ dcs, const int* __restrict__ label,
                        const float* __restrict__ scal, float* __restrict__ out) {
  if (threadIdx.x == 0 && blockIdx.x == 0) {
    float cd = 0.f;
    for (int c = 0; c < 20; ++c) {
      float lab = (float)label[c];
      cd += fmaxf(1.f - lab * dcs[c], 0.f);
    }
    cd *= (1.f / 20.f);
    float rl1 = -scal[0] / scal[1];
    float rl2 = -scal[2] / scal[3];
    out[0] = cd + 0.1f * (rl1 + rl2);
  }
}

// ---------------- workspace layout (all 16B aligned) ----------------
constexpr size_t OFF_S     = 0;                               // 1572864
constexpr size_t OFF_SCAL  = OFF_S + (size_t)N_ROWS * NC * 4; // 16
constexpr size_t OFF_DCS   = OFF_SCAL + 16;                   // 80
constexpr size_t OFF_B1    = OFF_DCS + 80;                    // 320
constexpr size_t OFF_B2    = OFF_B1 + 320;                    // 320
constexpr size_t OFF_LSE1  = OFF_B2 + 320;                    // 16384
constexpr size_t OFF_LSE2  = OFF_LSE1 + 16384;                // 16384
constexpr size_t OFF_CLSP  = OFF_LSE2 + 16384;                // 327680
constexpr size_t OFF_RP1   = OFF_CLSP + 327680;               // 344064
constexpr size_t OFF_WP    = OFF_RP1 + 344064;                // 786432
constexpr size_t OFF_SPART = OFF_WP + 786432;                 // 2*4096*96*4 = 3145728

extern "C" void kernel_launch(void* const* d_in, const int* in_sizes, int n_in,
                              void* d_out, int out_size, void* d_ws, size_t ws_size,
                              hipStream_t stream) {
  const float* roi   = (const float*)d_in[0];
  const float* ctx   = (const float*)d_in[1];
  const float* frame = (const float*)d_in[2];
  const float* Wcls  = (const float*)d_in[3];
  const float* bcls  = (const float*)d_in[4];
  const float* Wdet  = (const float*)d_in[5];
  const float* Wr1   = (const float*)d_in[7];
  const float* br1   = (const float*)d_in[8];
  const float* Wr2   = (const float*)d_in[9];
  const float* br2   = (const float*)d_in[10];
  const float* ssb   = (const float*)d_in[11];
  const float* isw   = (const float*)d_in[12];
  const int*   label = (const int*)d_in[13];

  char* ws = (char*)d_ws;
  float*  S     = (float*)(ws + OFF_S);
  float*  scal  = (float*)(ws + OFF_SCAL);
  float*  dcs   = (float*)(ws + OFF_DCS);
  float*  b1    = (float*)(ws + OFF_B1);
  float*  b2    = (float*)(ws + OFF_B2);
  float*  lse1  = (float*)(ws + OFF_LSE1);
  float*  lse2  = (float*)(ws + OFF_LSE2);
  float*  clsp  = (float*)(ws + OFF_CLSP);
  float*  rp1   = (float*)(ws + OFF_RP1);
  ushort* Wp    = (ushort*)(ws + OFF_WP);
  float*  Spart = (float*)(ws + OFF_SPART);

  hipMemsetAsync(scal, 0, 16, stream);
  k_pack<<<1536, 256, 0, stream>>>(Wcls, Wr1, Wr2, Wdet, Wp);
  k_gemm<<<512, 256, 0, stream>>>(roi, frame, ctx, Wp, Spart);
  k_rr<<<128, 256, 0, stream>>>(Spart, bcls, br1, br2, S, clsp, rp1, lse1, lse2);
  k_col<<<20, 256, 0, stream>>>(S, clsp, rp1, isw, ssb, bcls, dcs, b1, b2);
  k_sup<<<16, 256, 0, stream>>>(S, ssb, isw, label, b1, b2, lse1, lse2, br1, br2, scal);
  k_final<<<1, 64, 0, stream>>>(dcs, label, scal, (float*)d_out);
}